// Round 9
// baseline (105.981 us; speedup 1.0000x reference)
//
#include <hip/hip_runtime.h>

// Problem constants (from the reference)
#define BB     256   // batch
#define S      64    // SIZE
#define EE     4096  // E
#define NROWS  17    // 1 + ADDITIONAL

// native clang vector type
typedef float f32x4 __attribute__((ext_vector_type(4)));

// ---------------------------------------------------------------------------
// Kernel 1: per-batch weights. One wave (64 threads) per batch.
// Latency-minimal: ALL global loads issued up front (one round-trip),
// no LDS, no barriers; products via shfl_xor butterfly (all lanes busy).
// ---------------------------------------------------------------------------
__global__ __launch_bounds__(64) void split_weights_kernel(
    const float* __restrict__ keys,     // [BB][S]
    const float* __restrict__ offset,   // [BB][S]
    const int*   __restrict__ bits,     // [BB][16][S]
    float* __restrict__ W0,             // [BB][S]
    float* __restrict__ W1,             // [BB][S]
    float* __restrict__ keys_out)       // [BB][S]
{
    const int b    = blockIdx.x;
    const int lane = threadIdx.x;   // 0..63 == column index

    // ---- issue every global load now (independent, all in flight) ----
    const float off = offset[b * S + lane];
    int bitv[16];
    #pragma unroll
    for (int j = 0; j < 16; ++j)
        bitv[j] = bits[((size_t)b * 16 + j) * S + lane];

    const int loc = lane & 15;
    const int sec = lane & ~15;
    const int t   = loc >> 3;
    const int q   = loc & 7;
    const int c0  = sec + 2 * q;
    const int c1  = c0 + 1;
    const float k0 = keys[b * S + c0];
    const float k1 = keys[b * S + c1];

    // ---- 17 choice-row masks, replicated into every lane ----
    unsigned long long mask[NROWS];
    mask[0] = __ballot((int)rintf(off) == 1);   // jnp.round = half-even
    #pragma unroll
    for (int j = 0; j < 16; ++j)
        mask[1 + j] = __ballot(bitv[j] == 1);

    // ---- probability products: lane's factor, then 64-lane butterfly ----
    const float one_m_off = 1.0f - off;
    float prob[NROWS];
    #pragma unroll
    for (int j = 0; j < NROWS; ++j) {
        float v = ((mask[j] >> lane) & 1ull) ? off : one_m_off;
        #pragma unroll
        for (int d = 1; d < 64; d <<= 1)
            v *= __shfl_xor(v, d, 64);
        prob[j] = v;            // all lanes hold the full product
    }

    // ---- normalize over ALL 17, then zero later duplicates ----
    float sum = 0.0f;
    #pragma unroll
    for (int j = 0; j < NROWS; ++j) sum += prob[j];
    const float inv = 1.0f / sum;
    #pragma unroll
    for (int j = 0; j < NROWS; ++j) {
        bool dup = false;
        #pragma unroll
        for (int k = 0; k < NROWS; ++k)
            if (k < j) dup |= (mask[k] == mask[j]);
        prob[j] = dup ? 0.0f : prob[j] * inv;
    }

    // ---- per-column split weights (lane = column) ----
    float w0 = 0.0f, w1 = 0.0f;
    #pragma unroll
    for (int j = 0; j < NROWS; ++j) {
        if ((mask[j] >> lane) & 1ull) w1 += prob[j]; else w0 += prob[j];
    }
    W0[b * S + lane] = w0;
    W1[b * S + lane] = w1;

    // ---- keys_out via shuffles (need W at columns c0, c1) ----
    const float wa0 = __shfl(w0, c0, 64), wa1 = __shfl(w1, c0, 64);
    const float wb0 = __shfl(w0, c1, 64), wb1 = __shfl(w1, c1, 64);
    const float wa = t ? wa1 : wa0;
    const float wb = t ? wb1 : wb0;
    keys_out[b * S + lane] = wa * k0 + wb * k1;
}

// ---------------------------------------------------------------------------
// Kernel 2: pure-stream apply (R5/R8 structure, one-shot blocks).
// A/B change vs R8: loads are now PLAIN cached too (R8 measured plain
// stores >> nt stores; this tests the same question for the read path).
// ---------------------------------------------------------------------------
__global__ __launch_bounds__(256) void split_apply_kernel(
    const float* __restrict__ input,   // [BB][S][EE]
    const float* __restrict__ W0,      // [BB][S]
    const float* __restrict__ W1,      // [BB][S]
    float* __restrict__ out)           // [BB][S][EE]
{
    const int blk = blockIdx.x;
    const int b   = blk >> 5;
    const int pr  = blk & 31;
    const int sec = (pr >> 3) << 4;  // 0,16,32,48
    const int q   = pr & 7;
    const int c0  = sec + 2 * q;
    const int c1  = c0 + 1;
    const int r0  = sec + q;
    const int r1  = sec + 8 + q;

    const float wa0 = W0[b * S + c0], wb0 = W0[b * S + c1];
    const float wa1 = W1[b * S + c0], wb1 = W1[b * S + c1];

    const f32x4* __restrict__ in0 = (const f32x4*)(input + ((size_t)b * S + c0) * EE);
    const f32x4* __restrict__ in1 = (const f32x4*)(input + ((size_t)b * S + c1) * EE);
    f32x4* __restrict__ o0 = (f32x4*)(out + ((size_t)b * S + r0) * EE);
    f32x4* __restrict__ o1 = (f32x4*)(out + ((size_t)b * S + r1) * EE);

    const int tid = threadIdx.x;

    // issue all 8 input loads up front; compiler staggers vmcnt waits
    f32x4 x0[4], x1[4];
    #pragma unroll
    for (int it = 0; it < 4; ++it) {
        x0[it] = in0[tid + it * 256];   // plain cached load (A/B vs R8 nt)
        x1[it] = in1[tid + it * 256];
    }

    #pragma unroll
    for (int it = 0; it < 4; ++it) {
        const int idx = tid + it * 256;
        f32x4 y0, y1;
        y0.x = wa0 * x0[it].x + wb0 * x1[it].x;
        y0.y = wa0 * x0[it].y + wb0 * x1[it].y;
        y0.z = wa0 * x0[it].z + wb0 * x1[it].z;
        y0.w = wa0 * x0[it].w + wb0 * x1[it].w;
        y1.x = wa1 * x0[it].x + wb1 * x1[it].x;
        y1.y = wa1 * x0[it].y + wb1 * x1[it].y;
        y1.z = wa1 * x0[it].z + wb1 * x1[it].z;
        y1.w = wa1 * x0[it].w + wb1 * x1[it].w;
        o0[idx] = y0;          // plain cached store (kept from R8)
        o1[idx] = y1;
    }
}

extern "C" void kernel_launch(void* const* d_in, const int* in_sizes, int n_in,
                              void* d_out, int out_size, void* d_ws, size_t ws_size,
                              hipStream_t stream) {
    const float* input  = (const float*)d_in[0];   // [256,64,4096] f32
    const float* keys   = (const float*)d_in[1];   // [256,64] f32
    const float* offset = (const float*)d_in[2];   // [256,64] f32
    const int*   bits   = (const int*)  d_in[3];   // [256,16,64] i32

    float* out      = (float*)d_out;                  // [256,64,4096]
    float* keys_out = out + (size_t)BB * S * EE;      // [256,64]

    float* W0 = (float*)d_ws;          // [256*64]
    float* W1 = W0 + BB * S;           // [256*64]

    split_weights_kernel<<<BB, 64, 0, stream>>>(keys, offset, bits, W0, W1, keys_out);
    split_apply_kernel<<<BB * 32, 256, 0, stream>>>(input, W0, W1, out);
}

// Round 10
// 87.443 us; speedup vs baseline: 1.2120x; 1.2120x over previous
//
#include <hip/hip_runtime.h>

// Problem constants (from the reference)
#define BB     256   // batch
#define S      64    // SIZE
#define EE     4096  // E
#define NROWS  17    // 1 + ADDITIONAL

// native clang vector type (HIP's float4 is a class; the nontemporal
// builtins require a true vector/scalar type)
typedef float f32x4 __attribute__((ext_vector_type(4)));

// ---------------------------------------------------------------------------
// Kernel 1: per-batch weights. One wave (64 threads) per batch.
// Latency-minimal: ALL global loads issued up front (one round-trip),
// no LDS, no barriers; products via shfl_xor butterfly (all lanes busy).
// ---------------------------------------------------------------------------
__global__ __launch_bounds__(64) void split_weights_kernel(
    const float* __restrict__ keys,     // [BB][S]
    const float* __restrict__ offset,   // [BB][S]
    const int*   __restrict__ bits,     // [BB][16][S]
    float* __restrict__ W0,             // [BB][S]
    float* __restrict__ W1,             // [BB][S]
    float* __restrict__ keys_out)       // [BB][S]
{
    const int b    = blockIdx.x;
    const int lane = threadIdx.x;   // 0..63 == column index

    // ---- issue every global load now (independent, all in flight) ----
    const float off = offset[b * S + lane];
    int bitv[16];
    #pragma unroll
    for (int j = 0; j < 16; ++j)
        bitv[j] = bits[((size_t)b * 16 + j) * S + lane];

    const int loc = lane & 15;
    const int sec = lane & ~15;
    const int t   = loc >> 3;
    const int q   = loc & 7;
    const int c0  = sec + 2 * q;
    const int c1  = c0 + 1;
    const float k0 = keys[b * S + c0];
    const float k1 = keys[b * S + c1];

    // ---- 17 choice-row masks, replicated into every lane ----
    unsigned long long mask[NROWS];
    mask[0] = __ballot((int)rintf(off) == 1);   // jnp.round = half-even
    #pragma unroll
    for (int j = 0; j < 16; ++j)
        mask[1 + j] = __ballot(bitv[j] == 1);

    // ---- probability products: lane's factor, then 64-lane butterfly ----
    const float one_m_off = 1.0f - off;
    float prob[NROWS];
    #pragma unroll
    for (int j = 0; j < NROWS; ++j) {
        float v = ((mask[j] >> lane) & 1ull) ? off : one_m_off;
        #pragma unroll
        for (int d = 1; d < 64; d <<= 1)
            v *= __shfl_xor(v, d, 64);
        prob[j] = v;            // all lanes hold the full product
    }

    // ---- normalize over ALL 17, then zero later duplicates ----
    float sum = 0.0f;
    #pragma unroll
    for (int j = 0; j < NROWS; ++j) sum += prob[j];
    const float inv = 1.0f / sum;
    #pragma unroll
    for (int j = 0; j < NROWS; ++j) {
        bool dup = false;
        #pragma unroll
        for (int k = 0; k < NROWS; ++k)
            if (k < j) dup |= (mask[k] == mask[j]);
        prob[j] = dup ? 0.0f : prob[j] * inv;
    }

    // ---- per-column split weights (lane = column) ----
    float w0 = 0.0f, w1 = 0.0f;
    #pragma unroll
    for (int j = 0; j < NROWS; ++j) {
        if ((mask[j] >> lane) & 1ull) w1 += prob[j]; else w0 += prob[j];
    }
    W0[b * S + lane] = w0;
    W1[b * S + lane] = w1;

    // ---- keys_out via shuffles (need W at columns c0, c1) ----
    const float wa0 = __shfl(w0, c0, 64), wa1 = __shfl(w1, c0, 64);
    const float wb0 = __shfl(w0, c1, 64), wb1 = __shfl(w1, c1, 64);
    const float wa = t ? wa1 : wa0;
    const float wb = t ? wb1 : wb0;
    keys_out[b * S + lane] = wa * k0 + wb * k1;
}

// ---------------------------------------------------------------------------
// Kernel 2: pure-stream apply — measured-optimal memory policy:
//   loads  = NONTEMPORAL  (input never reused; keeps L2/L3 unpolluted,
//            preserving write-back buffering for the output stream;
//            plain loads cost +18 us [R9 A/B])
//   stores = PLAIN cached (write-back batching through L2/L3;
//            nt stores cost +8 us [R8 A/B])
// One block per (batch, column-pair): rows r0=sec+q, r1=sec+8+q both consume
// input rows c0=sec+2q, c1=c0+1. Input read exactly once, output written once.
// ---------------------------------------------------------------------------
__global__ __launch_bounds__(256) void split_apply_kernel(
    const float* __restrict__ input,   // [BB][S][EE]
    const float* __restrict__ W0,      // [BB][S]
    const float* __restrict__ W1,      // [BB][S]
    float* __restrict__ out)           // [BB][S][EE]
{
    const int blk = blockIdx.x;
    const int b   = blk >> 5;
    const int pr  = blk & 31;
    const int sec = (pr >> 3) << 4;  // 0,16,32,48
    const int q   = pr & 7;
    const int c0  = sec + 2 * q;
    const int c1  = c0 + 1;
    const int r0  = sec + q;
    const int r1  = sec + 8 + q;

    const float wa0 = W0[b * S + c0], wb0 = W0[b * S + c1];
    const float wa1 = W1[b * S + c0], wb1 = W1[b * S + c1];

    const f32x4* __restrict__ in0 = (const f32x4*)(input + ((size_t)b * S + c0) * EE);
    const f32x4* __restrict__ in1 = (const f32x4*)(input + ((size_t)b * S + c1) * EE);
    f32x4* __restrict__ o0 = (f32x4*)(out + ((size_t)b * S + r0) * EE);
    f32x4* __restrict__ o1 = (f32x4*)(out + ((size_t)b * S + r1) * EE);

    const int tid = threadIdx.x;

    // issue all 8 input loads up front; compiler staggers vmcnt waits
    f32x4 x0[4], x1[4];
    #pragma unroll
    for (int it = 0; it < 4; ++it) {
        x0[it] = __builtin_nontemporal_load(&in0[tid + it * 256]);
        x1[it] = __builtin_nontemporal_load(&in1[tid + it * 256]);
    }

    #pragma unroll
    for (int it = 0; it < 4; ++it) {
        const int idx = tid + it * 256;
        f32x4 y0, y1;
        y0.x = wa0 * x0[it].x + wb0 * x1[it].x;
        y0.y = wa0 * x0[it].y + wb0 * x1[it].y;
        y0.z = wa0 * x0[it].z + wb0 * x1[it].z;
        y0.w = wa0 * x0[it].w + wb0 * x1[it].w;
        y1.x = wa1 * x0[it].x + wb1 * x1[it].x;
        y1.y = wa1 * x0[it].y + wb1 * x1[it].y;
        y1.z = wa1 * x0[it].z + wb1 * x1[it].z;
        y1.w = wa1 * x0[it].w + wb1 * x1[it].w;
        o0[idx] = y0;          // plain cached store (measured optimum)
        o1[idx] = y1;
    }
}

extern "C" void kernel_launch(void* const* d_in, const int* in_sizes, int n_in,
                              void* d_out, int out_size, void* d_ws, size_t ws_size,
                              hipStream_t stream) {
    const float* input  = (const float*)d_in[0];   // [256,64,4096] f32
    const float* keys   = (const float*)d_in[1];   // [256,64] f32
    const float* offset = (const float*)d_in[2];   // [256,64] f32
    const int*   bits   = (const int*)  d_in[3];   // [256,16,64] i32

    float* out      = (float*)d_out;                  // [256,64,4096]
    float* keys_out = out + (size_t)BB * S * EE;      // [256,64]

    float* W0 = (float*)d_ws;          // [256*64]
    float* W1 = W0 + BB * S;           // [256*64]

    split_weights_kernel<<<BB, 64, 0, stream>>>(keys, offset, bits, W0, W1, keys_out);
    split_apply_kernel<<<BB * 32, 256, 0, stream>>>(input, W0, W1, out);
}